// Round 1
// baseline (272.595 us; speedup 1.0000x reference)
//
#include <hip/hip_runtime.h>
#include <math.h>

// Problem dims
#define NB 64
#define NA 23
#define NT 128
#define ND 256
#define NAE 32
#define NS 6
#define NH 8
#define NDM 288

// Workspace layout (float offsets)
#define OFF_PET    0                 // peT[e][t] : 256*128
#define OFF_PECUM  32768             // PEcum[L][e] : 129*256 (rows 1..128 used)
#define OFF_WKT    65792             // WkT[j][e] = Wk[e][j]/sqrt(32) : 256*288
#define OFF_VWO    139520            // VWo[h][e] : 8*288
#define OFF_CST    141824            // [0..5]=sWf, [6]=b_static.Wg1+bg, [7]=bo.Wg0, [8..15]=vb[h]
#define OFF_S      141840            // s[b][a] : 1472
// total floats = 143312  (573,248 bytes of ws)

__global__ __launch_bounds__(256) void setup_kernel(
    const float* __restrict__ Wk, const float* __restrict__ Wv,
    const float* __restrict__ Wo, const float* __restrict__ Wg,
    const float* __restrict__ bv, const float* __restrict__ bo,
    const float* __restrict__ W_static, const float* __restrict__ b_static,
    const float* __restrict__ bg, float* __restrict__ ws)
{
    const int tid = threadIdx.x;
    float* peT   = ws + OFF_PET;
    float* PEcum = ws + OFF_PECUM;
    float* WkT   = ws + OFF_WKT;
    float* VWo   = ws + OFF_VWO;
    float* cst   = ws + OFF_CST;

    // pe table (transposed) + prefix sums. pe[t, 2i]=sin(t*div_i), pe[t,2i+1]=cos
    {
        const int e = tid;                 // 0..255
        const int i = e >> 1;
        const float kdiv = 0.07195578415606394f; // ln(10000)/128
        const float dv = __expf(-(float)i * kdiv);
        float cum = 0.f;
        for (int t = 0; t < NT; ++t) {
            float ang = (float)t * dv;
            float v = (e & 1) ? cosf(ang) : sinf(ang);
            peT[e * NT + t] = v;
            cum += v;
            PEcum[(t + 1) * ND + e] = cum;
        }
    }
    // WkT scaled by 1/sqrt(DK)
    {
        const float scale = 0.17677669529663687f; // 1/sqrt(32)
        for (int idx = tid; idx < ND * NDM; idx += 256) {
            int j = idx / NDM, e = idx % NDM;
            WkT[idx] = Wk[e * ND + j] * scale;
        }
    }
    // WoWg[j] = sum_m Wo[j,m]*Wg[m]  (Wg0 = Wg[0:288])
    __shared__ float WoWg[ND];
    {
        float acc = 0.f;
        const float* row = Wo + tid * NDM;
        for (int m = 0; m < NDM; ++m) acc = fmaf(row[m], Wg[m], acc);
        WoWg[tid] = acc;
    }
    __syncthreads();
    // VWo[h][e] = sum_{jj<32} Wv[e, h*32+jj]*WoWg[h*32+jj]
    for (int idx = tid; idx < NH * NDM; idx += 256) {
        int h = idx / NDM, e = idx % NDM;
        float acc = 0.f;
        for (int jj = 0; jj < 32; ++jj)
            acc = fmaf(Wv[e * ND + h * 32 + jj], WoWg[h * 32 + jj], acc);
        VWo[idx] = acc;
    }
    // constants
    if (tid < 6) {
        float acc = 0.f;
        for (int m = 0; m < ND; ++m) acc = fmaf(W_static[tid * ND + m], Wg[NDM + m], acc);
        cst[tid] = acc;
    } else if (tid == 6) {
        float acc = bg[0];
        for (int m = 0; m < ND; ++m) acc = fmaf(b_static[m], Wg[NDM + m], acc);
        cst[6] = acc;
    } else if (tid == 7) {
        float acc = 0.f;
        for (int m = 0; m < NDM; ++m) acc = fmaf(bo[m], Wg[m], acc);
        cst[7] = acc;
    } else if (tid >= 8 && tid < 16) {
        int h = tid - 8;
        float acc = 0.f;
        for (int jj = 0; jj < 32; ++jj)
            acc = fmaf(bv[h * 32 + jj], WoWg[h * 32 + jj], acc);
        cst[8 + h] = acc;
    }
}

__global__ __launch_bounds__(256) void main_kernel(
    const float* __restrict__ data, const int* __restrict__ lengths,
    const float* __restrict__ W_embed, const float* __restrict__ b_embed,
    const float* __restrict__ E_var,
    const float* __restrict__ Wq, const float* __restrict__ bq,
    float* __restrict__ ws)
{
    const int wg = blockIdx.x;        // b*23 + a
    const int a = wg % NA;
    const int tid = threadIdx.x;
    const int L = lengths[wg];        // wave-uniform

    if (L == 0) {
        if (tid == 0) ws[OFF_S + wg] = 0.f;
        return;
    }

    __shared__ float xs[NT];
    __shared__ float agentwise[NDM];
    __shared__ float qs[ND];
    __shared__ float2 Wb[ND];
    __shared__ __align__(16) float combo[ND * 16];  // per e<256: {qk[e][0..3], VWo[0..3][e], qk[e][4..7], VWo[4..7][e]}
    __shared__ float sc[NH * NT];
    __shared__ float mvb[NH * NT];
    __shared__ float evvS[NH];
    __shared__ float red[4];

    const float* peT   = ws + OFF_PET;
    const float* PEcum = ws + OFF_PECUM;
    const float* WkT   = ws + OFF_WKT;
    const float* VWo   = ws + OFF_VWO;
    const float* cstp  = ws + OFF_CST;

    // ---- Phase A: load x row, W/b rows, agentwise via pe prefix table ----
    if (tid < NT) xs[tid] = data[wg * NT + tid];
    __syncthreads();
    {
        const int e = tid;   // 0..255
        const float We = W_embed[a * ND + e];
        const float be = b_embed[a * ND + e];
        Wb[e] = make_float2(We, be);
        float acc = 0.f;
        #pragma unroll 4
        for (int t = 0; t < L; ++t)
            acc += fmaxf(fmaf(xs[t], We, be), 0.f);
        agentwise[e] = (acc + PEcum[L * ND + e]) / (float)L;
    }
    if (tid < NAE) agentwise[ND + tid] = E_var[a * NAE + tid];
    __syncthreads();

    // ---- Phase C: q[j] = agentwise . Wq[:,j] + bq[j] ----
    {
        const int j = tid;
        float acc = bq[j];
        #pragma unroll 4
        for (int f = 0; f < NDM; ++f)
            acc = fmaf(agentwise[f], Wq[f * ND + j], acc);
        qs[j] = acc;
    }
    __syncthreads();

    // ---- Phase D: qk[e][h] (e<256) into combo; copy VWo; evv ----
    {
        const int h = tid >> 5, eo = tid & 31;
        const float* wr = WkT + (h * 32) * NDM;
        for (int eb = 0; eb < 8; ++eb) {       // e < 256 only
            int e = eb * 32 + eo;
            float acc = 0.f;
            #pragma unroll 8
            for (int j = 0; j < 32; ++j)
                acc = fmaf(wr[j * NDM + e], qs[h * 32 + j], acc);
            combo[e * 16 + (h >> 2) * 8 + (h & 3)] = acc;
        }
    }
    for (int idx = tid; idx < NH * ND; idx += 256) {
        int h = idx >> 8, e = idx & 255;
        combo[e * 16 + (h >> 2) * 8 + 4 + (h & 3)] = VWo[h * NDM + e];
    }
    {
        const int h = tid >> 5, ee = tid & 31;
        float v = E_var[a * NAE + ee] * VWo[h * NDM + ND + ee];
        v += __shfl_down(v, 16, 32);
        v += __shfl_down(v, 8, 32);
        v += __shfl_down(v, 4, 32);
        v += __shfl_down(v, 2, 32);
        v += __shfl_down(v, 1, 32);
        if (ee == 0) evvS[h] = v;
    }
    __syncthreads();

    // ---- Phase E: scores[t,h] and mv[t,h] with on-the-fly mem recompute ----
    {
        const int t = tid & 127;
        const int g = tid >> 7;            // which 4-head group
        const float xt = xs[t];
        float4 accS = make_float4(0.f, 0.f, 0.f, 0.f);
        float4 accM = make_float4(0.f, 0.f, 0.f, 0.f);
        const float* peCol = peT + t;
        const float4* comboV = (const float4*)combo;
        #pragma unroll 4
        for (int e = 0; e < ND; ++e) {
            float2 wb = Wb[e];
            float m = fmaxf(fmaf(xt, wb.x, wb.y), 0.f) + peCol[e * NT];
            float4 cq = comboV[e * 4 + g * 2];
            float4 cv = comboV[e * 4 + g * 2 + 1];
            accS.x = fmaf(m, cq.x, accS.x);
            accS.y = fmaf(m, cq.y, accS.y);
            accS.z = fmaf(m, cq.z, accS.z);
            accS.w = fmaf(m, cq.w, accS.w);
            accM.x = fmaf(m, cv.x, accM.x);
            accM.y = fmaf(m, cv.y, accM.y);
            accM.z = fmaf(m, cv.z, accM.z);
            accM.w = fmaf(m, cv.w, accM.w);
        }
        const int hb = g * 4;
        sc[(hb + 0) * NT + t] = accS.x;
        sc[(hb + 1) * NT + t] = accS.y;
        sc[(hb + 2) * NT + t] = accS.z;
        sc[(hb + 3) * NT + t] = accS.w;
        mvb[(hb + 0) * NT + t] = accM.x;
        mvb[(hb + 1) * NT + t] = accM.y;
        mvb[(hb + 2) * NT + t] = accM.z;
        mvb[(hb + 3) * NT + t] = accM.w;
    }
    __syncthreads();

    // ---- Phase F: per-head softmax over t<L, s_h = sum_t p*(mv+vb+evv) ----
    {
        const int wv = tid >> 6, lane = tid & 63;
        float wsum = 0.f;
        for (int hh = 0; hh < 2; ++hh) {
            const int h = wv * 2 + hh;
            float s1 = (lane < L) ? sc[h * NT + lane] : -3e38f;
            float s2 = (lane + 64 < L) ? sc[h * NT + 64 + lane] : -3e38f;
            float mx = fmaxf(s1, s2);
            #pragma unroll
            for (int off = 32; off > 0; off >>= 1)
                mx = fmaxf(mx, __shfl_down(mx, off, 64));
            mx = __shfl(mx, 0, 64);
            const float vbv = evvS[h] + cstp[8 + h];
            float e1 = (lane < L) ? __expf(s1 - mx) : 0.f;
            float e2 = (lane + 64 < L) ? __expf(s2 - mx) : 0.f;
            float num = e1 * (mvb[h * NT + lane] + vbv);
            num = fmaf(e2, mvb[h * NT + 64 + lane] + vbv, num);
            float den = e1 + e2;
            #pragma unroll
            for (int off = 32; off > 0; off >>= 1) {
                num += __shfl_down(num, off, 64);
                den += __shfl_down(den, off, 64);
            }
            if (lane == 0) wsum += num / den;
        }
        if (lane == 0) red[wv] = wsum;
    }
    __syncthreads();
    if (tid == 0) {
        ws[OFF_S + wg] = cstp[7] + red[0] + red[1] + red[2] + red[3];
    }
}

__global__ __launch_bounds__(64) void final_kernel(
    const float* __restrict__ statics, const int* __restrict__ lengths,
    const float* __restrict__ ws, float* __restrict__ out)
{
    const int b = threadIdx.x;   // 64 threads, one per batch
    const float* s_arr = ws + OFF_S;
    const float* cst = ws + OFF_CST;
    float sum = 0.f;
    int n = 0;
    for (int a = 0; a < NA; ++a) {
        if (lengths[b * NA + a] > 0) { sum += s_arr[b * NA + a]; ++n; }
    }
    float o = sum / ((float)n + 1e-9f);
    #pragma unroll
    for (int i = 0; i < NS; ++i)
        o = fmaf(statics[b * NS + i], cst[i], o);
    o += cst[6];
    out[b] = o;
}

extern "C" void kernel_launch(void* const* d_in, const int* in_sizes, int n_in,
                              void* d_out, int out_size, void* d_ws, size_t ws_size,
                              hipStream_t stream) {
    const float* data     = (const float*)d_in[0];
    // d_in[1] = time  (implied by mask; unused)
    const int*   mask     = (const int*)d_in[2];
    const float* statics  = (const float*)d_in[3];
    const float* W_embed  = (const float*)d_in[4];
    const float* b_embed  = (const float*)d_in[5];
    const float* E_var    = (const float*)d_in[6];
    const float* W_static = (const float*)d_in[7];
    const float* b_static = (const float*)d_in[8];
    const float* Wq       = (const float*)d_in[9];
    const float* bq       = (const float*)d_in[10];
    const float* Wk       = (const float*)d_in[11];
    // d_in[12] = bk (uniform over t -> cancels in softmax; unused)
    const float* Wv       = (const float*)d_in[13];
    const float* bv       = (const float*)d_in[14];
    const float* Wo       = (const float*)d_in[15];
    const float* bo       = (const float*)d_in[16];
    const float* Wg       = (const float*)d_in[17];
    const float* bg       = (const float*)d_in[18];
    float* out = (float*)d_out;
    float* ws  = (float*)d_ws;

    setup_kernel<<<dim3(1), dim3(256), 0, stream>>>(Wk, Wv, Wo, Wg, bv, bo,
                                                    W_static, b_static, bg, ws);
    main_kernel<<<dim3(NB * NA), dim3(256), 0, stream>>>(data, mask, W_embed, b_embed,
                                                         E_var, Wq, bq, ws);
    final_kernel<<<dim3(1), dim3(64), 0, stream>>>(statics, mask, ws, out);
}

// Round 2
// 169.161 us; speedup vs baseline: 1.6115x; 1.6115x over previous
//
#include <hip/hip_runtime.h>
#include <math.h>

// Problem dims
#define NB 64
#define NA 23
#define NT 128
#define ND 256
#define NAE 32
#define NS 6
#define NH 8
#define NDM 288

// Workspace layout (float offsets)
#define OFF_PET    0                 // peT[e][t] : 256*128
#define OFF_PECUM  32768             // PEcum[L][e] : 129*256 (rows 1..128 used)
#define OFF_WKT    65792             // WkT[j][e<256] = Wk[e][j]/sqrt(32) : 256*256
#define OFF_VWO    131328            // VWo[h][e] : 8*288
#define OFF_CST    133632            // [0..5]=sWf, [6]=b_static.Wg1+bg, [7]=bo.Wg0, [8..15]=vb[h]
#define OFF_S      133648            // s[b][a] : 1472
// total floats = 135120 (540,480 bytes of ws)

// Parallel setup: 393 blocks.
//  blocks [0,128)   : pe table + prefix scan, 2 e-columns per block
//  blocks [128,384) : WkT transpose, one j-row per block
//  blocks [384,392) : per-head VWo (+ redundant WoWg slice) + cst[8+h]
//  block  392       : cst[0..7]
__global__ __launch_bounds__(256) void setup_kernel(
    const float* __restrict__ Wk, const float* __restrict__ Wv,
    const float* __restrict__ Wo, const float* __restrict__ Wg,
    const float* __restrict__ bv, const float* __restrict__ bo,
    const float* __restrict__ W_static, const float* __restrict__ b_static,
    const float* __restrict__ bg, float* __restrict__ ws)
{
    const int blk = blockIdx.x;
    const int tid = threadIdx.x;
    float* peT   = ws + OFF_PET;
    float* PEcum = ws + OFF_PECUM;
    float* WkT   = ws + OFF_WKT;
    float* VWo   = ws + OFF_VWO;
    float* cst   = ws + OFF_CST;

    if (blk < 128) {
        // pe: e = blk*2 + (tid>>7), t = tid&127. One transcendental per thread.
        const int g = tid >> 7, t = tid & 127;
        const int e = blk * 2 + g;
        const int i = e >> 1;
        const float kdiv = 0.07195578415606394f; // ln(10000)/128
        const float dv = expf(-(float)i * kdiv);
        const float ang = (float)t * dv;
        const float v = (e & 1) ? cosf(ang) : sinf(ang);
        peT[e * NT + t] = v;
        __shared__ float buf[256];
        buf[tid] = v;
        // inclusive Hillis-Steele scan over t within each 128-group
        #pragma unroll
        for (int s = 1; s < 128; s <<= 1) {
            __syncthreads();
            float add = (t >= s) ? buf[tid - s] : 0.f;
            __syncthreads();
            buf[tid] += add;
        }
        __syncthreads();
        PEcum[(t + 1) * ND + e] = buf[tid];
    } else if (blk < 384) {
        // WkT[j][e] = Wk[e][j] * 1/sqrt(32), e<256 only (E_var cols cancel in softmax)
        const int j = blk - 128;
        const float scale = 0.17677669529663687f;
        WkT[j * 256 + tid] = Wk[tid * ND + j] * scale;
    } else if (blk < 392) {
        const int h = blk - 384;
        __shared__ float wog[32];   // WoWg[h*32 + jj]
        {
            const int jj = tid >> 3, sub = tid & 7;   // 8 lanes per jj
            const int j = h * 32 + jj;
            float acc = 0.f;
            const int m0 = sub * 36;                  // 288 = 8*36
            #pragma unroll 4
            for (int m = m0; m < m0 + 36; ++m)
                acc = fmaf(Wo[j * NDM + m], Wg[m], acc);
            acc += __shfl_down(acc, 4, 8);
            acc += __shfl_down(acc, 2, 8);
            acc += __shfl_down(acc, 1, 8);
            if (sub == 0) wog[jj] = acc;
        }
        __syncthreads();
        for (int e = tid; e < NDM; e += 256) {
            float acc = 0.f;
            #pragma unroll 8
            for (int jj = 0; jj < 32; ++jj)
                acc = fmaf(Wv[e * ND + h * 32 + jj], wog[jj], acc);
            VWo[h * NDM + e] = acc;
        }
        if (tid == 0) {
            float acc = 0.f;
            #pragma unroll 8
            for (int jj = 0; jj < 32; ++jj)
                acc = fmaf(bv[h * 32 + jj], wog[jj], acc);
            cst[8 + h] = acc;
        }
    } else {
        // cst[0..7]: 32 lanes per output
        const int i = tid >> 5, sub = tid & 31;
        float acc = 0.f;
        if (i < 6) {
            for (int m = sub; m < 256; m += 32)
                acc = fmaf(W_static[i * ND + m], Wg[NDM + m], acc);
        } else if (i == 6) {
            for (int m = sub; m < 256; m += 32)
                acc = fmaf(b_static[m], Wg[NDM + m], acc);
        } else {
            for (int m = sub; m < NDM; m += 32)
                acc = fmaf(bo[m], Wg[m], acc);
        }
        #pragma unroll
        for (int off = 16; off > 0; off >>= 1)
            acc += __shfl_down(acc, off, 32);
        if (sub == 0) cst[i] = (i == 6) ? acc + bg[0] : acc;
    }
}

__global__ __launch_bounds__(256) void main_kernel(
    const float* __restrict__ data, const int* __restrict__ lengths,
    const float* __restrict__ W_embed, const float* __restrict__ b_embed,
    const float* __restrict__ E_var,
    const float* __restrict__ Wq, const float* __restrict__ bq,
    float* __restrict__ ws)
{
    const int wg = blockIdx.x;        // b*23 + a
    const int a = wg % NA;
    const int tid = threadIdx.x;
    const int L = lengths[wg];        // wave-uniform

    if (L == 0) {
        if (tid == 0) ws[OFF_S + wg] = 0.f;
        return;
    }

    __shared__ float xs[NT];
    __shared__ float agentwise[NDM];
    __shared__ float qs[ND];
    __shared__ float2 Wb[ND];
    // combo: per e<256, 16 floats: {qk[e][0..7], VWo[0..7][e]}.
    // Dead after Phase E -> aliased as sc/mvb/partials (saves 8 KB LDS).
    __shared__ __align__(16) float combo[ND * 16];
    __shared__ float evvS[NH];
    __shared__ float red[4];

    const float* peT   = ws + OFF_PET;
    const float* PEcum = ws + OFF_PECUM;
    const float* WkT   = ws + OFF_WKT;
    const float* VWo   = ws + OFF_VWO;
    const float* cstp  = ws + OFF_CST;

    // ---- Phase A: load x row, W/b rows, agentwise via pe prefix table ----
    if (tid < NT) xs[tid] = data[wg * NT + tid];
    __syncthreads();
    {
        const int e = tid;   // 0..255
        const float We = W_embed[a * ND + e];
        const float be = b_embed[a * ND + e];
        Wb[e] = make_float2(We, be);
        float acc = 0.f;
        #pragma unroll 4
        for (int t = 0; t < L; ++t)
            acc += fmaxf(fmaf(xs[t], We, be), 0.f);
        agentwise[e] = (acc + PEcum[L * ND + e]) / (float)L;
    }
    if (tid < NAE) agentwise[ND + tid] = E_var[a * NAE + tid];
    __syncthreads();

    // ---- Phase C: q[j] = agentwise . Wq[:,j] + bq[j] ----
    {
        const int j = tid;
        float acc = bq[j];
        #pragma unroll 4
        for (int f = 0; f < NDM; ++f)
            acc = fmaf(agentwise[f], Wq[f * ND + j], acc);
        qs[j] = acc;
    }
    __syncthreads();

    // ---- Phase D: qk[e][h] into combo; copy VWo; evv ----
    {
        const int h = tid >> 5, eo = tid & 31;
        const float* wr = WkT + (h * 32) * 256;
        for (int eb = 0; eb < 8; ++eb) {
            const int e = eb * 32 + eo;
            float acc = 0.f;
            #pragma unroll 8
            for (int j = 0; j < 32; ++j)
                acc = fmaf(wr[j * 256 + e], qs[h * 32 + j], acc);
            combo[e * 16 + h] = acc;
        }
    }
    for (int idx = tid; idx < NH * ND; idx += 256) {
        const int h = idx >> 8, e = idx & 255;
        combo[e * 16 + 8 + h] = VWo[h * NDM + e];
    }
    {
        const int h = tid >> 5, ee = tid & 31;
        float v = E_var[a * NAE + ee] * VWo[h * NDM + ND + ee];
        v += __shfl_down(v, 16, 32);
        v += __shfl_down(v, 8, 32);
        v += __shfl_down(v, 4, 32);
        v += __shfl_down(v, 2, 32);
        v += __shfl_down(v, 1, 32);
        if (ee == 0) evvS[h] = v;
    }
    __syncthreads();

    // ---- Phase E: each half-block does 128 e-values for ALL 8 heads ----
    {
        const int t = tid & 127;
        const int half = tid >> 7;
        const float xt = xs[t];
        float accS[8], accM[8];
        #pragma unroll
        for (int h = 0; h < 8; ++h) { accS[h] = 0.f; accM[h] = 0.f; }
        const int ebase = half * 128;
        const float4* comboV = (const float4*)combo + ebase * 4;
        const float* peCol = peT + ebase * NT + t;
        #pragma unroll 2
        for (int ee = 0; ee < 128; ++ee) {
            const float2 wb = Wb[ebase + ee];
            const float m = fmaxf(fmaf(xt, wb.x, wb.y), 0.f) + peCol[ee * NT];
            const float4 c0 = comboV[ee * 4 + 0];  // qk h0..3
            const float4 c1 = comboV[ee * 4 + 1];  // qk h4..7
            const float4 c2 = comboV[ee * 4 + 2];  // VWo h0..3
            const float4 c3 = comboV[ee * 4 + 3];  // VWo h4..7
            accS[0] = fmaf(m, c0.x, accS[0]);
            accS[1] = fmaf(m, c0.y, accS[1]);
            accS[2] = fmaf(m, c0.z, accS[2]);
            accS[3] = fmaf(m, c0.w, accS[3]);
            accS[4] = fmaf(m, c1.x, accS[4]);
            accS[5] = fmaf(m, c1.y, accS[5]);
            accS[6] = fmaf(m, c1.z, accS[6]);
            accS[7] = fmaf(m, c1.w, accS[7]);
            accM[0] = fmaf(m, c2.x, accM[0]);
            accM[1] = fmaf(m, c2.y, accM[1]);
            accM[2] = fmaf(m, c2.z, accM[2]);
            accM[3] = fmaf(m, c2.w, accM[3]);
            accM[4] = fmaf(m, c3.x, accM[4]);
            accM[5] = fmaf(m, c3.y, accM[5]);
            accM[6] = fmaf(m, c3.z, accM[6]);
            accM[7] = fmaf(m, c3.w, accM[7]);
        }
        __syncthreads();   // all combo reads done -> safe to reuse region
        float* sc   = combo;
        float* mvb  = combo + 1024;
        float* scP1 = combo + 2048;
        float* mvP1 = combo + 3072;
        if (half == 1) {
            #pragma unroll
            for (int h = 0; h < 8; ++h) {
                scP1[h * NT + t] = accS[h];
                mvP1[h * NT + t] = accM[h];
            }
        }
        __syncthreads();
        if (half == 0) {
            #pragma unroll
            for (int h = 0; h < 8; ++h) {
                sc[h * NT + t]  = accS[h] + scP1[h * NT + t];
                mvb[h * NT + t] = accM[h] + mvP1[h * NT + t];
            }
        }
    }
    __syncthreads();

    // ---- Phase F: per-head softmax over t<L, s_h = sum_t p*(mv+vb+evv) ----
    {
        const float* sc  = combo;
        const float* mvb = combo + 1024;
        const int wv = tid >> 6, lane = tid & 63;
        float wsum = 0.f;
        for (int hh = 0; hh < 2; ++hh) {
            const int h = wv * 2 + hh;
            float s1 = (lane < L) ? sc[h * NT + lane] : -3e38f;
            float s2 = (lane + 64 < L) ? sc[h * NT + 64 + lane] : -3e38f;
            float mx = fmaxf(s1, s2);
            #pragma unroll
            for (int off = 32; off > 0; off >>= 1)
                mx = fmaxf(mx, __shfl_down(mx, off, 64));
            mx = __shfl(mx, 0, 64);
            const float vbv = evvS[h] + cstp[8 + h];
            float e1 = (lane < L) ? __expf(s1 - mx) : 0.f;
            float e2 = (lane + 64 < L) ? __expf(s2 - mx) : 0.f;
            float num = e1 * (mvb[h * NT + lane] + vbv);
            num = fmaf(e2, mvb[h * NT + 64 + lane] + vbv, num);
            float den = e1 + e2;
            #pragma unroll
            for (int off = 32; off > 0; off >>= 1) {
                num += __shfl_down(num, off, 64);
                den += __shfl_down(den, off, 64);
            }
            if (lane == 0) wsum += num / den;
        }
        if (lane == 0) red[wv] = wsum;
    }
    __syncthreads();
    if (tid == 0) {
        ws[OFF_S + wg] = cstp[7] + red[0] + red[1] + red[2] + red[3];
    }
}

__global__ __launch_bounds__(64) void final_kernel(
    const float* __restrict__ statics, const int* __restrict__ lengths,
    const float* __restrict__ ws, float* __restrict__ out)
{
    const int b = threadIdx.x;   // 64 threads, one per batch
    const float* s_arr = ws + OFF_S;
    const float* cst = ws + OFF_CST;
    float sum = 0.f;
    int n = 0;
    for (int a = 0; a < NA; ++a) {
        if (lengths[b * NA + a] > 0) { sum += s_arr[b * NA + a]; ++n; }
    }
    float o = sum / ((float)n + 1e-9f);
    #pragma unroll
    for (int i = 0; i < NS; ++i)
        o = fmaf(statics[b * NS + i], cst[i], o);
    o += cst[6];
    out[b] = o;
}

extern "C" void kernel_launch(void* const* d_in, const int* in_sizes, int n_in,
                              void* d_out, int out_size, void* d_ws, size_t ws_size,
                              hipStream_t stream) {
    const float* data     = (const float*)d_in[0];
    // d_in[1] = time  (implied by mask; unused)
    const int*   mask     = (const int*)d_in[2];
    const float* statics  = (const float*)d_in[3];
    const float* W_embed  = (const float*)d_in[4];
    const float* b_embed  = (const float*)d_in[5];
    const float* E_var    = (const float*)d_in[6];
    const float* W_static = (const float*)d_in[7];
    const float* b_static = (const float*)d_in[8];
    const float* Wq       = (const float*)d_in[9];
    const float* bq       = (const float*)d_in[10];
    const float* Wk       = (const float*)d_in[11];
    // d_in[12] = bk (uniform over t -> cancels in softmax; unused)
    const float* Wv       = (const float*)d_in[13];
    const float* bv       = (const float*)d_in[14];
    const float* Wo       = (const float*)d_in[15];
    const float* bo       = (const float*)d_in[16];
    const float* Wg       = (const float*)d_in[17];
    const float* bg       = (const float*)d_in[18];
    float* out = (float*)d_out;
    float* ws  = (float*)d_ws;

    setup_kernel<<<dim3(393), dim3(256), 0, stream>>>(Wk, Wv, Wo, Wg, bv, bo,
                                                      W_static, b_static, bg, ws);
    main_kernel<<<dim3(NB * NA), dim3(256), 0, stream>>>(data, mask, W_embed, b_embed,
                                                         E_var, Wq, bq, ws);
    final_kernel<<<dim3(1), dim3(64), 0, stream>>>(statics, mask, ws, out);
}